// Round 9
// baseline (1606.320 us; speedup 1.0000x reference)
//
#include <hip/hip_runtime.h>

#define Bb 256
#define Tt 512
#define Dd 64
#define Hh 256
#define NP 16
#define HB2 (256 * 256)  // f16 elements per h slot (4 slots per layer)
#define FSTRIDE 16       // dwords between flags: one 64B line per flag

typedef unsigned short u16;
typedef _Float16 f16;
typedef __attribute__((ext_vector_type(8))) _Float16 f16x8;
typedef __attribute__((ext_vector_type(4))) _Float16 f16x4;
typedef __attribute__((ext_vector_type(4))) float f32x4;
typedef __attribute__((ext_vector_type(4))) unsigned int u32x4;

__device__ __forceinline__ f16x8 bc8h(u32x4 v) { return __builtin_bit_cast(f16x8, v); }

__device__ __forceinline__ float fsig(float x) {
  x = fminf(fmaxf(x, -30.f), 30.f);
  return 1.f / (1.f + __expf(-x));
}
__device__ __forceinline__ float ftanh(float x) {
  x = fminf(fmaxf(x, -15.f), 15.f);
  float t = __expf(2.f * x);
  return (t - 1.f) / (t + 1.f);
}

// sc1 = device scope (L3/fabric) — the PROVEN cross-XCD path (flags, fallback h).
// sc0 loads are NOT L1-coherent (R5 lesson): only safe for streaming data whose
// footprint self-evicts from L1 (the 64KB rotating h slots).
__device__ __forceinline__ f16x8 ld16_sc1(const f16* p) {
  f16x8 r;
  asm volatile("global_load_dwordx4 %0, %1, off sc1" : "=v"(r) : "v"(p) : "memory");
  return r;
}
__device__ __forceinline__ f16x8 ld16_sc0(const f16* p) {
  f16x8 r;
  asm volatile("global_load_dwordx4 %0, %1, off sc0" : "=v"(r) : "v"(p) : "memory");
  return r;
}
__device__ __forceinline__ void st2_sc1(f16* p, unsigned v) {
  asm volatile("global_store_short %0, %1, off sc1" : : "v"(p), "v"(v) : "memory");
}
__device__ __forceinline__ void st2_plain(f16* p, unsigned v) {
  asm volatile("global_store_short %0, %1, off" : : "v"(p), "v"(v) : "memory");
}
__device__ __forceinline__ void st4u_plain(unsigned* p, unsigned v) {
  asm volatile("global_store_dword %0, %1, off" : : "v"(p), "v"(v) : "memory");
}
__device__ __forceinline__ void st4u_sc1(unsigned* p, unsigned v) {
  asm volatile("global_store_dword %0, %1, off sc1" : : "v"(p), "v"(v) : "memory");
}
__device__ __forceinline__ unsigned ld4_sc0(const unsigned* p) {
  unsigned r;
  asm volatile("global_load_dword %0, %1, off sc0\n\ts_waitcnt vmcnt(0)"
               : "=v"(r) : "v"(p) : "memory");
  return r;
}

__global__ __launch_bounds__(256) void prep_x(const float* __restrict__ x,
                                              f16* __restrict__ xh) {
  int i = blockIdx.x * blockDim.x + threadIdx.x;  // float4 index
  const int n4 = Bb * Tt * Dd / 4;
  if (i >= n4) return;
  f32x4 v = ((const f32x4*)x)[i];
  f16x4 o;
#pragma unroll
  for (int j = 0; j < 4; ++j) o[j] = (f16)v[j];
  ((f16x4*)xh)[i] = o;
}

// wfrag: [p16][wv8][f32][lane64][e8] f16.  (2^21 elements)
// wv<4 (layer0, gate=wv):  f0-3 Wih0 (kt=f>>1), f4-19 Whh0 (kt=(f-4)>>1), f>=20 zero
// wv>=4 (layer1, gate=wv-4): f0-15 Wih1 (kt=f>>1), f16-31 Whh1 (kt=(f-16)>>1)
// f even = fp16(w) ; f odd = fp16((w - hi) * 2048)   [scaled lo part]
__global__ __launch_bounds__(256) void prep_w(
    const float* __restrict__ wih0, const float* __restrict__ whh0,
    const float* __restrict__ bih0, const float* __restrict__ bhh0,
    const float* __restrict__ wih1, const float* __restrict__ whh1,
    const float* __restrict__ bih1, const float* __restrict__ bhh1,
    f16* __restrict__ wfrag, float* __restrict__ bias0s, float* __restrict__ bias1s) {
  int tid = blockIdx.x * blockDim.x + threadIdx.x;
  int np = gridDim.x * blockDim.x;
  const int tot = 16 * 8 * 32 * 512;  // 2^21
  for (int u = tid; u < tot; u += np) {
    int e = u & 7, l = (u >> 3) & 63;
    int f = (u >> 9) & 31;
    int wv = (u >> 14) & 7;
    int p = u >> 17;
    int g = wv & 3;
    int grow = g * 256 + p * 16 + (l & 15);
    int klane = (l >> 4) * 8 + e;
    float w = 0.f;
    if (wv < 4) {
      if (f < 4)       w = wih0[grow * 64 + (f >> 1) * 32 + klane];
      else if (f < 20) w = whh0[grow * 256 + ((f - 4) >> 1) * 32 + klane];
    } else {
      if (f < 16)      w = wih1[grow * 256 + (f >> 1) * 32 + klane];
      else             w = whh1[grow * 256 + ((f - 16) >> 1) * 32 + klane];
    }
    f16 hi = (f16)w;
    wfrag[u] = (f & 1) ? (f16)((w - (float)hi) * 2048.0f) : hi;
  }
  for (int u = tid; u < 1024; u += np) {
    bias0s[u] = bih0[u] + bhh0[u];
    bias1s[u] = bih1[u] + bhh1[u];
  }
}

#define MF(A, B, C) __builtin_amdgcn_mfma_f32_16x16x32_f16(A, B, C, 0, 0, 0)

// 512 blocks x 256 threads (4 waves = 4 gates), 2 blocks/CU (launch_bounds 256,2
// is MANDATORY: all 512 blocks must be co-resident or the spin protocol stalls).
// bids 0-255: layer-0 role; bids 256-511: layer-1 role (pipelined 1 step behind).
// Same (grp,p) mapping per role; bid and bid+256 share bid%8 -> same XCD under
// round-robin, so the whole 32-block group pair is co-XCD (probe-verified).
// Flags: h0flags[grp,p] = #completed L0 iters; l1flags[grp,p] = last L1 iter.
//   L0 step k: needs h0flags>=k (data h0(k-1)) && l1flags>=k-3 (slot reuse).
//   L1 step k: needs h0flags>=k (data h0(k-1)) && l1flags>=k-1 (data h1(k-1)).
// Poll has a 65536-iter cap: a protocol bug surfaces as wrong output + counters,
// never a 600s timeout.
__global__ __launch_bounds__(256, 2) void lstm_persist(
    const f16* __restrict__ xh, const f16* __restrict__ wfrag,
    const float* __restrict__ bias0s, const float* __restrict__ bias1s,
    f16* h0, f16* h1, unsigned* h0flags, unsigned* l1flags, unsigned* probe,
    unsigned* verdict) {
  const int bid = blockIdx.x;
  const bool L1blk = bid >= 256;
  const int b = bid & 255;
  const int p = (b >> 3) & 15;
  const int grp = (b & 7) * 2 + (b >> 7);
  const int tid = threadIdx.x;
  const int wv = tid >> 6, lane = tid & 63;  // wv = gate 0..3
  const int lr = lane & 15, lk = lane >> 4;
  const int g = wv;
  const float LOSCALE = 1.0f / 2048.0f;
  const int NPP = 32;  // group-pair size (16 L0 + 16 L1 blocks)

  __shared__ float gbuf[4][16][16];
  // Staged h (prev slot): [layer][row16][chunk36(pad)] of 16B; chunk index
  // XOR-swizzled with (row&7). L0 blocks use layer 0 only.
  __shared__ u32x4 hbuf[2][16][36];
  __shared__ unsigned s_fast;

  // Weight fragments: resident for all 512 steps (VGPR+AGPR unified file).
  f16x8 wf[32];
  {
    const u32x4* wp =
        (const u32x4*)wfrag + ((size_t)(p * 8 + (L1blk ? 4 + g : g)) * 32) * 64 + lane;
#pragma unroll
    for (int f = 0; f < 20; ++f) wf[f] = bc8h(wp[(size_t)f * 64]);
    if (L1blk) {
#pragma unroll
      for (int f = 20; f < 32; ++f) wf[f] = bc8h(wp[(size_t)f * 64]);
    }
  }
  const float bias = (L1blk ? bias1s : bias0s)[g * 256 + p * 16 + lr];

  // ---- zero-init own slice of the slot read at the first step, both flavors:
  //      L0 reads h0 slot3 at k=0; L1 reads h1 slot0 at k=1 ----
  if (tid < 128) {
    int row = tid >> 3, cp = tid & 7;
    f16* base = L1blk ? h1 : (h0 + (size_t)3 * HB2);
    unsigned* w = (unsigned*)(base + (size_t)(grp * 16 + row) * 256 + p * 16) + cp;
    st4u_plain(w, 0u);
    st4u_sc1(w, 0u);
  }
  asm volatile("s_waitcnt vmcnt(0)" ::: "memory");
  __syncthreads();

  // ---- probe: prove all 32 group-pair blocks share this block's L2 ----
  if (wv == 0) {
    const int myslot = grp * NPP + (L1blk ? 16 : 0) + p;
    const unsigned mytok = (unsigned)((L1blk ? 16 : 0) + p + 1);
    if (lane == 0) {
      st4u_plain(&probe[myslot], mytok);
      asm volatile("s_waitcnt vmcnt(0)" ::: "memory");
    }
    bool seen = (lane >= NPP);
    bool ok;
    int it = 0;
    while (true) {
      if (!seen) {
        unsigned got = ld4_sc0(&probe[grp * NPP + lane]);
        if (got == (unsigned)(lane + 1)) seen = true;
      }
      if (__all(seen)) { ok = true; break; }
      if (++it > 1536) { ok = false; break; }
      __builtin_amdgcn_s_sleep(2);
    }
    if (lane == 0)
      __hip_atomic_store(&verdict[myslot], ok ? 1u : 2u, __ATOMIC_RELAXED,
                         __HIP_MEMORY_SCOPE_AGENT);
    unsigned v;
    while (true) {
      v = 1u;
      if (lane < NPP)
        v = __hip_atomic_load(&verdict[grp * NPP + lane], __ATOMIC_RELAXED,
                              __HIP_MEMORY_SCOPE_AGENT);
      if (!__any(v == 0u)) break;
      __builtin_amdgcn_s_sleep(2);
    }
    if (lane == 0) s_fast = __any(v != 1u) ? 0u : 1u;
  }
  __syncthreads();
  const bool fast = (s_fast != 0u);

  // Elementwise ownership: one cell element per thread (256 = 16x16 slice).
  const int erow = tid >> 4, ecol = tid & 15;
  float c = 0.f;
  f16* const hout =
      (L1blk ? h1 : h0) + (size_t)(grp * 16 + erow) * 256 + p * 16 + ecol;

  const int hrow = grp * 16 + lr;
  const f16* xbase = xh + (size_t)hrow * Tt * Dd + lk * 8;
  const f16* h0src = h0 + (size_t)grp * 4096;
  const f16* h1src = h1 + (size_t)grp * 4096;

  for (int s = 0; s < Tt; ++s) {
    const int k = s + (L1blk ? 1 : 0);

    // ---- flag-independent work first: x load + x-part MFMAs (L0 role) ----
    f32x4 a0 = (f32x4){bias, bias, bias, bias};
    f32x4 b0 = (f32x4){0.f, 0.f, 0.f, 0.f};
    f32x4 a1 = (f32x4){0.f, 0.f, 0.f, 0.f};
    f32x4 b1 = (f32x4){0.f, 0.f, 0.f, 0.f};
    if (!L1blk) {
      const u32x4* xp = (const u32x4*)(xbase + (size_t)k * Dd);
      f16x8 xf0 = bc8h(xp[0]);
      f16x8 xf1 = bc8h(xp[4]);
      a0 = MF(xf0, wf[0], a0);
      b0 = MF(xf0, wf[1], b0);
      a1 = MF(xf1, wf[2], a1);
      b1 = MF(xf1, wf[3], b1);
    }

    // ---- wave 0 polls (padded sc1 lines): lanes 0-15 h0flags, 16-31 l1flags ----
    if (wv == 0) {
      const unsigned thrA = (unsigned)k;
      const unsigned thrB =
          L1blk ? (unsigned)(k - 1) : (unsigned)(k >= 3 ? k - 3 : 0);
      int it = 0;
      bool ready = false;
      while (!ready) {
        unsigned v = 0xFFFFFFFFu;
        if (lane < NP)
          v = __hip_atomic_load(&h0flags[(grp * NP + lane) * FSTRIDE],
                                __ATOMIC_RELAXED, __HIP_MEMORY_SCOPE_AGENT);
        else if (lane < 2 * NP)
          v = __hip_atomic_load(&l1flags[(grp * NP + lane - NP) * FSTRIDE],
                                __ATOMIC_RELAXED, __HIP_MEMORY_SCOPE_AGENT);
        const unsigned thr = (lane < NP) ? thrA : thrB;
        ready = !__any(v < thr);
        if (!ready) {
          if (++it > 65536) break;  // bug -> visible wrong answer, not a hang
          __builtin_amdgcn_s_sleep(1);
        }
      }
    }
    asm volatile("" ::: "memory");
    __syncthreads();

    const int par = (k - 1) & 3;

    // ---- stage h(k-1) into LDS: L0 stages h0 (8KB); L1 stages h0+h1 (16KB) ----
    {
      const int j0 = wv * 2;  // this wave's first 1KB chunk (of 8 per layer)
      const f16* p00 = h0src + (size_t)par * HB2 + j0 * 512 + lane * 8;
      f16x8 s0, s1, t0, t1;
      if (fast) {
        s0 = ld16_sc0(p00);
        s1 = ld16_sc0(p00 + 512);
      } else {
        s0 = ld16_sc1(p00);
        s1 = ld16_sc1(p00 + 512);
      }
      if (L1blk) {
        const f16* p10 = h1src + (size_t)par * HB2 + j0 * 512 + lane * 8;
        if (fast) {
          t0 = ld16_sc0(p10);
          t1 = ld16_sc0(p10 + 512);
        } else {
          t0 = ld16_sc1(p10);
          t1 = ld16_sc1(p10 + 512);
        }
      }
      asm volatile("s_waitcnt vmcnt(0)" ::: "memory");
      const int r0 = j0 * 2 + (lane >> 5);
      const int c2 = lane & 31;
      hbuf[0][r0][c2 ^ (r0 & 7)] = __builtin_bit_cast(u32x4, s0);
      hbuf[0][r0 + 2][c2 ^ ((r0 + 2) & 7)] = __builtin_bit_cast(u32x4, s1);
      if (L1blk) {
        hbuf[1][r0][c2 ^ (r0 & 7)] = __builtin_bit_cast(u32x4, t0);
        hbuf[1][r0 + 2][c2 ^ ((r0 + 2) & 7)] = __builtin_bit_cast(u32x4, t1);
      }
    }
    __syncthreads();

    // ---- A fragments from LDS + MFMA (split chains a0/b0 and a1/b1) ----
    f16x8 A0[8];
#pragma unroll
    for (int kt = 0; kt < 8; ++kt)
      A0[kt] = __builtin_bit_cast(f16x8, hbuf[0][lr][(kt * 4 + lk) ^ (lr & 7)]);
    if (!L1blk) {
#pragma unroll
      for (int kt = 0; kt < 8; kt += 2) {
        a0 = MF(A0[kt], wf[4 + 2 * kt], a0);
        b0 = MF(A0[kt], wf[5 + 2 * kt], b0);
        a1 = MF(A0[kt + 1], wf[6 + 2 * kt], a1);
        b1 = MF(A0[kt + 1], wf[7 + 2 * kt], b1);
      }
    } else {
      f16x8 A1[8];
#pragma unroll
      for (int kt = 0; kt < 8; ++kt)
        A1[kt] = __builtin_bit_cast(f16x8, hbuf[1][lr][(kt * 4 + lk) ^ (lr & 7)]);
#pragma unroll
      for (int kt = 0; kt < 8; kt += 2) {
        a0 = MF(A0[kt], wf[2 * kt], a0);
        b0 = MF(A0[kt], wf[2 * kt + 1], b0);
        a1 = MF(A0[kt + 1], wf[2 * kt + 2], a1);
        b1 = MF(A0[kt + 1], wf[2 * kt + 3], b1);
      }
#pragma unroll
      for (int kt = 0; kt < 8; kt += 2) {
        a0 = MF(A1[kt], wf[16 + 2 * kt], a0);
        b0 = MF(A1[kt], wf[17 + 2 * kt], b0);
        a1 = MF(A1[kt + 1], wf[18 + 2 * kt], a1);
        b1 = MF(A1[kt + 1], wf[19 + 2 * kt], b1);
      }
    }
    {
      f32x4 acc = (a0 + a1) + (b0 + b1) * LOSCALE;
#pragma unroll
      for (int r = 0; r < 4; ++r) gbuf[g][lk * 4 + r][lr] = acc[r];
    }
    __syncthreads();

    // ---- elementwise update + publish: all 256 threads, 1 element each ----
    {
      float iv = fsig(gbuf[0][erow][ecol]);
      float fv = fsig(gbuf[1][erow][ecol]);
      float gv = ftanh(gbuf[2][erow][ecol]);
      float ov = fsig(gbuf[3][erow][ecol]);
      c = fv * c + iv * gv;
      float hval = ov * ftanh(c);
      f16 fh = (f16)hval;
      unsigned bits = (unsigned)__builtin_bit_cast(u16, fh);
      f16* Ho = hout + (size_t)(k & 3) * HB2;
      if (fast) st2_plain(Ho, bits);
      else      st2_sc1(Ho, bits);
    }
    asm volatile("s_waitcnt vmcnt(0)" ::: "memory");
    __syncthreads();
    if (tid == 0) {
      unsigned* fp = (L1blk ? l1flags : h0flags) + (grp * NP + p) * FSTRIDE;
      unsigned nv = (unsigned)(L1blk ? k : k + 1);
      __hip_atomic_store(fp, nv, __ATOMIC_RELAXED, __HIP_MEMORY_SCOPE_AGENT);
    }
  }
}

__global__ __launch_bounds__(128) void head_kernel(
    const f16* __restrict__ h0f, const f16* __restrict__ h1f,
    const float* __restrict__ fc1w, const float* __restrict__ fc1b,
    const float* __restrict__ fc2w, const float* __restrict__ fc2b,
    float* __restrict__ out) {
  int r = blockIdx.x;
  const f16* hh = (r < 256) ? (h0f + r * Hh) : (h1f + (r - 256) * Hh);
  __shared__ float v[Hh];
  int tid = threadIdx.x;
  for (int i = tid; i < Hh; i += 128)
    v[i] = fmaxf((float)hh[i], 0.f);
  __syncthreads();
  float s = fc1b[tid];
#pragma unroll 8
  for (int i = 0; i < Hh; ++i) s += fc1w[tid * Hh + i] * v[i];
  s = fmaxf(s, 0.f) * fc2w[tid];
#pragma unroll
  for (int off = 32; off; off >>= 1) s += __shfl_down(s, off);
  __shared__ float red[2];
  if ((tid & 63) == 0) red[tid >> 6] = s;
  __syncthreads();
  if (tid == 0) out[r] = red[0] + red[1] + fc2b[0];
}

extern "C" void kernel_launch(void* const* d_in, const int* in_sizes, int n_in,
                              void* d_out, int out_size, void* d_ws, size_t ws_size,
                              hipStream_t stream) {
  (void)in_sizes; (void)n_in; (void)out_size; (void)ws_size;
  const float* x    = (const float*)d_in[0];
  const float* wih0 = (const float*)d_in[1];
  const float* whh0 = (const float*)d_in[2];
  const float* bih0 = (const float*)d_in[3];
  const float* bhh0 = (const float*)d_in[4];
  const float* wih1 = (const float*)d_in[5];
  const float* whh1 = (const float*)d_in[6];
  const float* bih1 = (const float*)d_in[7];
  const float* bhh1 = (const float*)d_in[8];
  const float* fc1w = (const float*)d_in[9];
  const float* fc1b = (const float*)d_in[10];
  const float* fc2w = (const float*)d_in[11];
  const float* fc2b = (const float*)d_in[12];

  char* ws = (char*)d_ws;
  size_t off = 0;
  f16* xh = (f16*)(ws + off); off += (size_t)Bb * Tt * Dd * 2;
  f16* wfrag = (f16*)(ws + off); off += (size_t)16 * 8 * 32 * 512 * 2;
  float* bias0s = (float*)(ws + off); off += 4096;
  float* bias1s = (float*)(ws + off); off += 4096;
  char* zbase = ws + off;
  f16* h0 = (f16*)(ws + off); off += (size_t)4 * HB2 * 2;  // 4 slots
  f16* h1 = (f16*)(ws + off); off += (size_t)4 * HB2 * 2;  // 4 slots
  unsigned* h0flags = (unsigned*)(ws + off); off += 256 * FSTRIDE * 4;
  unsigned* l1flags = (unsigned*)(ws + off); off += 256 * FSTRIDE * 4;
  unsigned* probe = (unsigned*)(ws + off); off += 2048;
  unsigned* verdict = (unsigned*)(ws + off); off += 2048;
  size_t zbytes = (size_t)((ws + off) - zbase);

  hipMemsetAsync(zbase, 0, zbytes, stream);
  prep_x<<<Bb * Tt * Dd / 4 / 256, 256, 0, stream>>>(x, xh);
  prep_w<<<512, 256, 0, stream>>>(wih0, whh0, bih0, bhh0, wih1, whh1, bih1, bhh1,
                                  wfrag, bias0s, bias1s);
  lstm_persist<<<512, 256, 0, stream>>>(xh, wfrag, bias0s, bias1s, h0, h1,
                                        h0flags, l1flags, probe, verdict);
  // final h0 written at iter 511 -> slot 3; final h1 at L1 iter 512 -> slot 0
  head_kernel<<<512, 128, 0, stream>>>(h0 + (size_t)3 * HB2, h1, fc1w, fc1b,
                                       fc2w, fc2b, (float*)d_out);
}

// Round 10
// 1424.966 us; speedup vs baseline: 1.1273x; 1.1273x over previous
//
#include <hip/hip_runtime.h>

#define Bb 256
#define Tt 512
#define Dd 64
#define Hh 256
#define NP 16
#define HB2 (256 * 256)  // f16 elements per h slot (4 slots per layer)
#define FSTRIDE 16       // dwords between flag counters: one 64B line each

typedef unsigned short u16;
typedef _Float16 f16;
typedef __attribute__((ext_vector_type(8))) _Float16 f16x8;
typedef __attribute__((ext_vector_type(4))) _Float16 f16x4;
typedef __attribute__((ext_vector_type(4))) float f32x4;
typedef __attribute__((ext_vector_type(4))) unsigned int u32x4;

__device__ __forceinline__ f16x8 bc8h(u32x4 v) { return __builtin_bit_cast(f16x8, v); }

__device__ __forceinline__ float fsig(float x) {
  x = fminf(fmaxf(x, -30.f), 30.f);
  return 1.f / (1.f + __expf(-x));
}
__device__ __forceinline__ float ftanh(float x) {
  x = fminf(fmaxf(x, -15.f), 15.f);
  float t = __expf(2.f * x);
  return (t - 1.f) / (t + 1.f);
}

// sc1 = device scope (L3/fabric) — proven cross-XCD path (slow-mode fallback).
// sc0 loads are NOT L1-coherent (R5): only for streaming data that self-evicts
// L1 (the 64KB rotating h slots). Hot flag lines use ATOMICS (L1-immune, R7).
__device__ __forceinline__ f16x8 ld16_sc1(const f16* p) {
  f16x8 r;
  asm volatile("global_load_dwordx4 %0, %1, off sc1" : "=v"(r) : "v"(p) : "memory");
  return r;
}
__device__ __forceinline__ f16x8 ld16_sc0(const f16* p) {
  f16x8 r;
  asm volatile("global_load_dwordx4 %0, %1, off sc0" : "=v"(r) : "v"(p) : "memory");
  return r;
}
__device__ __forceinline__ void st2_sc1(f16* p, unsigned v) {
  asm volatile("global_store_short %0, %1, off sc1" : : "v"(p), "v"(v) : "memory");
}
__device__ __forceinline__ void st2_plain(f16* p, unsigned v) {
  asm volatile("global_store_short %0, %1, off" : : "v"(p), "v"(v) : "memory");
}
__device__ __forceinline__ void st4u_plain(unsigned* p, unsigned v) {
  asm volatile("global_store_dword %0, %1, off" : : "v"(p), "v"(v) : "memory");
}
__device__ __forceinline__ void st4u_sc1(unsigned* p, unsigned v) {
  asm volatile("global_store_dword %0, %1, off sc1" : : "v"(p), "v"(v) : "memory");
}
__device__ __forceinline__ unsigned ld4_sc0(const unsigned* p) {
  unsigned r;
  asm volatile("global_load_dword %0, %1, off sc0\n\ts_waitcnt vmcnt(0)"
               : "=v"(r) : "v"(p) : "memory");
  return r;
}
// Fire-and-forget atomics — execute at the local XCD L2 (no sc1). [R7-proven]
__device__ __forceinline__ void atomswap_l2(unsigned* p, unsigned v) {
  asm volatile("global_atomic_swap %0, %1, off" : : "v"(p), "v"(v) : "memory");
}
__device__ __forceinline__ void atomadd_l2(unsigned* p, unsigned v) {
  asm volatile("global_atomic_add %0, %1, off" : : "v"(p), "v"(v) : "memory");
}
// Coherent read via atomic add 0 (sc0 = return old); bypasses L1. [R7-proven]
__device__ __forceinline__ unsigned atomadd0_l2(unsigned* p) {
  unsigned r;
  asm volatile("global_atomic_add %0, %1, %2, off sc0\n\ts_waitcnt vmcnt(0)"
               : "=v"(r) : "v"(p), "v"(0u) : "memory");
  return r;
}

__global__ __launch_bounds__(256) void prep_x(const float* __restrict__ x,
                                              f16* __restrict__ xh) {
  int i = blockIdx.x * blockDim.x + threadIdx.x;  // float4 index
  const int n4 = Bb * Tt * Dd / 4;
  if (i >= n4) return;
  f32x4 v = ((const f32x4*)x)[i];
  f16x4 o;
#pragma unroll
  for (int j = 0; j < 4; ++j) o[j] = (f16)v[j];
  ((f16x4*)xh)[i] = o;
}

// wfrag: [p16][wv8][f32][lane64][e8] f16.  (2^21 elements)
// wv<4 (layer0, gate=wv):  f0-3 Wih0 (kt=f>>1), f4-19 Whh0 (kt=(f-4)>>1), f>=20 zero
// wv>=4 (layer1, gate=wv-4): f0-15 Wih1 (kt=f>>1), f16-31 Whh1 (kt=(f-16)>>1)
// f even = fp16(w) ; f odd = fp16((w - hi) * 2048)   [scaled lo part]
__global__ __launch_bounds__(256) void prep_w(
    const float* __restrict__ wih0, const float* __restrict__ whh0,
    const float* __restrict__ bih0, const float* __restrict__ bhh0,
    const float* __restrict__ wih1, const float* __restrict__ whh1,
    const float* __restrict__ bih1, const float* __restrict__ bhh1,
    f16* __restrict__ wfrag, float* __restrict__ bias0s, float* __restrict__ bias1s) {
  int tid = blockIdx.x * blockDim.x + threadIdx.x;
  int np = gridDim.x * blockDim.x;
  const int tot = 16 * 8 * 32 * 512;  // 2^21
  for (int u = tid; u < tot; u += np) {
    int e = u & 7, l = (u >> 3) & 63;
    int f = (u >> 9) & 31;
    int wv = (u >> 14) & 7;
    int p = u >> 17;
    int g = wv & 3;
    int grow = g * 256 + p * 16 + (l & 15);
    int klane = (l >> 4) * 8 + e;
    float w = 0.f;
    if (wv < 4) {
      if (f < 4)       w = wih0[grow * 64 + (f >> 1) * 32 + klane];
      else if (f < 20) w = whh0[grow * 256 + ((f - 4) >> 1) * 32 + klane];
    } else {
      if (f < 16)      w = wih1[grow * 256 + (f >> 1) * 32 + klane];
      else             w = whh1[grow * 256 + ((f - 16) >> 1) * 32 + klane];
    }
    f16 hi = (f16)w;
    wfrag[u] = (f & 1) ? (f16)((w - (float)hi) * 2048.0f) : hi;
  }
  for (int u = tid; u < 1024; u += np) {
    bias0s[u] = bih0[u] + bhh0[u];
    bias1s[u] = bih1[u] + bhh1[u];
  }
}

#define MF(A, B, C) __builtin_amdgcn_mfma_f32_16x16x32_f16(A, B, C, 0, 0, 0)

// 256 blocks (1/CU), 512 threads (8 waves).
// waves 0-3: layer0 gate wv; waves 4-7: layer1 gate wv-4.
// Group remap: p=(bid>>3)&15, grp=(bid&7)*2+(bid>>7) -> group shares one XCD
// (probe-verified each run; R4: FETCH 600->60MB on engage).
// Sync: per-partition COUNTER (one 64B line), +1 per wave after its h-store ack;
// ready for step k <=> all 16 counters >= 8k. Wave 0 polls (L2 atomics fast /
// agent atomics slow) and posts to an LDS mailbox; waves 1-7 spin on LDS.
// 2 barriers per step (down from 4): [stage+ds_write] BAR [MFMA+gbuf] BAR
// [elem + h store + ack + count++] -> loop.
__global__ __launch_bounds__(512, 1) void lstm_persist(
    const f16* __restrict__ xh, const f16* __restrict__ wfrag,
    const float* __restrict__ bias0s, const float* __restrict__ bias1s,
    f16* h0, f16* h1, unsigned* flagcnt, unsigned* probe, unsigned* verdict) {
  const int bid = blockIdx.x;
  const int p = (bid >> 3) & 15;
  const int grp = (bid & 7) * 2 + (bid >> 7);
  const int tid = threadIdx.x;
  const int wv = tid >> 6, lane = tid & 63;
  const int lr = lane & 15, lk = lane >> 4;
  const int g = wv & 3;
  const bool isL1 = wv >= 4;
  const float LOSCALE = 1.0f / 2048.0f;

  __shared__ float gbuf[2][4][16][16];
  // Staged h (prev slot): [layer][row16][chunk36(pad)] of 16B; chunk index
  // XOR-swizzled with (row&7); row stride 36 chunks spreads banks.
  __shared__ u32x4 hbuf[2][16][36];
  __shared__ unsigned s_fast;
  __shared__ int s_mbox;

  if (tid == 0) s_mbox = -1;

  // Weight fragments: resident for all 512 steps (unified VGPR/AGPR file).
  f16x8 wf[32];
  {
    const u32x4* wp = (const u32x4*)wfrag + ((size_t)(p * 8 + wv) * 32) * 64 + lane;
#pragma unroll
    for (int f = 0; f < 20; ++f) wf[f] = bc8h(wp[(size_t)f * 64]);
    if (isL1) {
#pragma unroll
      for (int f = 20; f < 32; ++f) wf[f] = bc8h(wp[(size_t)f * 64]);
    }
  }
  const float bias = (isL1 ? bias1s : bias0s)[g * 256 + p * 16 + lr];

  // ---- zero-init the slices read at k=0 (h0 slot 3) and k=1 (h1 slot 0),
  //      through BOTH store flavors, and our counter via BOTH atomic paths
  //      (kills stale L2/L3 lines from a previous graph replay) ----
  if (tid < 256) {
    int lsel = tid >> 7;   // 0 -> h0 slot3, 1 -> h1 slot0
    int d = tid & 127;
    int row = d >> 3, cp = d & 7;
    f16* base = lsel ? h1 : (h0 + (size_t)3 * HB2);
    unsigned* w = (unsigned*)(base + (size_t)(grp * 16 + row) * 256 + p * 16) + cp;
    st4u_plain(w, 0u);
    st4u_sc1(w, 0u);
  }
  if (tid == 0) {
    atomswap_l2(&flagcnt[(grp * NP + p) * FSTRIDE], 0u);
    __hip_atomic_store(&flagcnt[(grp * NP + p) * FSTRIDE], 0u, __ATOMIC_RELAXED,
                       __HIP_MEMORY_SCOPE_AGENT);
  }
  asm volatile("s_waitcnt vmcnt(0)" ::: "memory");
  __syncthreads();

  // ---- probe: prove all 16 group blocks share this block's L2 ----
  if (wv == 0) {
    if (lane == 0) {
      st4u_plain(&probe[grp * NP + p], (unsigned)(p + 1));
      asm volatile("s_waitcnt vmcnt(0)" ::: "memory");
    }
    bool seen = (lane >= NP);
    bool ok;
    int it = 0;
    while (true) {
      if (!seen) {
        unsigned got = ld4_sc0(&probe[grp * NP + lane]);
        if (got == (unsigned)(lane + 1)) seen = true;
      }
      if (__all(seen)) { ok = true; break; }
      if (++it > 768) { ok = false; break; }
      __builtin_amdgcn_s_sleep(2);
    }
    if (lane == 0)
      __hip_atomic_store(&verdict[grp * NP + p], ok ? 1u : 2u, __ATOMIC_RELAXED,
                         __HIP_MEMORY_SCOPE_AGENT);
    // gather verdicts (guaranteed to arrive: probe is bounded)
    unsigned v;
    while (true) {
      v = 1u;
      if (lane < NP)
        v = __hip_atomic_load(&verdict[grp * NP + lane], __ATOMIC_RELAXED,
                              __HIP_MEMORY_SCOPE_AGENT);
      if (!__any(v == 0u)) break;
      __builtin_amdgcn_s_sleep(2);
    }
    if (lane == 0) s_fast = __any(v != 1u) ? 0u : 1u;
  }
  __syncthreads();
  const bool fast = (s_fast != 0u);

  // Elementwise ownership: one cell element per thread (512 = 2 layers x 256).
  const int eL = tid >> 8;               // 0: waves 0-3 (L0), 1: waves 4-7 (L1)
  const int erow = (tid >> 4) & 15, ecol = tid & 15;
  float c = 0.f;
  f16* const hout = ((eL ? h1 : h0) + (size_t)(grp * 16 + erow) * 256 + p * 16 + ecol);

  const int hrow = grp * 16 + lr;
  const f16* xbase = xh + (size_t)hrow * Tt * Dd + lk * 8;
  // Staging source: waves 0-3 load h0, waves 4-7 load h1 (group's 16 rows).
  const f16* hsrcbase = ((wv < 4) ? h0 : h1) + (size_t)grp * 4096;
  const int hlsel = wv >> 2;
  unsigned* const mycnt = &flagcnt[(grp * NP + p) * FSTRIDE];

  for (int k = 0; k <= Tt; ++k) {
    // ---- flag-independent work first: x load + x-part MFMAs (layer 0) ----
    f32x4 a = (f32x4){bias, bias, bias, bias};
    f32x4 b = (f32x4){0.f, 0.f, 0.f, 0.f};
    if (!isL1 && k < Tt) {
      const u32x4* xp = (const u32x4*)(xbase + (size_t)k * Dd);
      f16x8 xf0 = bc8h(xp[0]);
      f16x8 xf1 = bc8h(xp[4]);
      a = MF(xf0, wf[0], a);
      b = MF(xf0, wf[1], b);
      a = MF(xf1, wf[2], a);
      b = MF(xf1, wf[3], b);
    }

    // ---- wave 0 polls counters, posts LDS mailbox; waves 1-7 spin on LDS ----
    if (wv == 0) {
      const unsigned thr = 8u * (unsigned)k;
      int it = 0;
      bool ready = false;
      while (!ready) {
        unsigned v = 0xFFFFFFFFu;
        if (lane < NP) {
          if (fast)
            v = atomadd0_l2(&flagcnt[(grp * NP + lane) * FSTRIDE]);
          else
            v = __hip_atomic_load(&flagcnt[(grp * NP + lane) * FSTRIDE],
                                  __ATOMIC_RELAXED, __HIP_MEMORY_SCOPE_AGENT);
        }
        ready = !__any(v < thr);
        if (!ready) {
          if (++it > 65536) break;  // bug -> wrong answer + counters, no hang
          __builtin_amdgcn_s_sleep(1);
        }
      }
      __hip_atomic_store(&s_mbox, k, __ATOMIC_RELAXED,
                         __HIP_MEMORY_SCOPE_WORKGROUP);
    } else {
      while (__hip_atomic_load(&s_mbox, __ATOMIC_RELAXED,
                               __HIP_MEMORY_SCOPE_WORKGROUP) < k)
        __builtin_amdgcn_s_sleep(1);
    }
    asm volatile("" ::: "memory");

    const int par = (k - 1) & 3;

    // ---- stage group's h (prev slot) into LDS (16KB total, per-wave 2KB) ----
    {
      const f16* src = hsrcbase + (size_t)par * HB2;
      const int j0 = (wv & 3) * 2;  // this wave's first 1KB chunk (of 8)
      const f16* p0 = src + j0 * 512 + lane * 8;
      f16x8 s0, s1;
      if (fast) {
        s0 = ld16_sc0(p0);
        s1 = ld16_sc0(p0 + 512);
      } else {
        s0 = ld16_sc1(p0);
        s1 = ld16_sc1(p0 + 512);
      }
      asm volatile("s_waitcnt vmcnt(0)" ::: "memory");
      const int r0 = j0 * 2 + (lane >> 5);  // row within group's 16
      const int c2 = lane & 31;             // 16B chunk within row
      hbuf[hlsel][r0][c2 ^ (r0 & 7)] = __builtin_bit_cast(u32x4, s0);
      hbuf[hlsel][r0 + 2][c2 ^ ((r0 + 2) & 7)] = __builtin_bit_cast(u32x4, s1);
    }
    __syncthreads();  // BAR1: hbuf writes done; prior gbuf reads done

    // ---- A fragments from LDS (swizzled reads) + MFMA ----
    f16x8 A0[8], A1[8];
#pragma unroll
    for (int kt = 0; kt < 8; ++kt)
      A0[kt] = __builtin_bit_cast(f16x8, hbuf[0][lr][(kt * 4 + lk) ^ (lr & 7)]);
    if (isL1) {
#pragma unroll
      for (int kt = 0; kt < 8; ++kt)
        A1[kt] = __builtin_bit_cast(f16x8, hbuf[1][lr][(kt * 4 + lk) ^ (lr & 7)]);
    }

    if (!isL1) {
      if (k < Tt) {
#pragma unroll
        for (int kt = 0; kt < 8; ++kt) {
          a = MF(A0[kt], wf[4 + 2 * kt], a);
          b = MF(A0[kt], wf[5 + 2 * kt], b);
        }
        a += b * LOSCALE;
#pragma unroll
        for (int r = 0; r < 4; ++r) gbuf[0][g][lk * 4 + r][lr] = a[r];
      }
    } else if (k >= 1) {
#pragma unroll
      for (int kt = 0; kt < 8; ++kt) {
        a = MF(A0[kt], wf[2 * kt], a);
        b = MF(A0[kt], wf[2 * kt + 1], b);
      }
#pragma unroll
      for (int kt = 0; kt < 8; ++kt) {
        a = MF(A1[kt], wf[16 + 2 * kt], a);
        b = MF(A1[kt], wf[17 + 2 * kt], b);
      }
      a += b * LOSCALE;
#pragma unroll
      for (int r = 0; r < 4; ++r) gbuf[1][g][lk * 4 + r][lr] = a[r];
    }
    __syncthreads();  // BAR2: gbuf ready; hbuf reads done

    // ---- elementwise + publish: all 512 threads, 1 element each; then each
    //      wave independently acks its stores and bumps the counter ----
    {
      const bool upd = eL ? (k >= 1) : (k < Tt);
      if (upd) {
        float iv = fsig(gbuf[eL][0][erow][ecol]);
        float fv = fsig(gbuf[eL][1][erow][ecol]);
        float gv = ftanh(gbuf[eL][2][erow][ecol]);
        float ov = fsig(gbuf[eL][3][erow][ecol]);
        c = fv * c + iv * gv;
        float hval = ov * ftanh(c);
        f16 fh = (f16)hval;
        unsigned bits = (unsigned)__builtin_bit_cast(u16, fh);
        f16* Ho = hout + (size_t)(k & 3) * HB2;
        if (fast) st2_plain(Ho, bits);
        else      st2_sc1(Ho, bits);
      }
    }
    asm volatile("s_waitcnt vmcnt(0)" ::: "memory");  // h stores at L2/L3
    if (lane == 0) {
      if (fast) atomadd_l2(mycnt, 1u);
      else (void)__hip_atomic_fetch_add(mycnt, 1u, __ATOMIC_RELAXED,
                                        __HIP_MEMORY_SCOPE_AGENT);
    }
    // no barrier: next iteration's mailbox/stage provides the ordering
  }
}

__global__ __launch_bounds__(128) void head_kernel(
    const f16* __restrict__ h0f, const f16* __restrict__ h1f,
    const float* __restrict__ fc1w, const float* __restrict__ fc1b,
    const float* __restrict__ fc2w, const float* __restrict__ fc2b,
    float* __restrict__ out) {
  int r = blockIdx.x;
  const f16* hh = (r < 256) ? (h0f + r * Hh) : (h1f + (r - 256) * Hh);
  __shared__ float v[Hh];
  int tid = threadIdx.x;
  for (int i = tid; i < Hh; i += 128)
    v[i] = fmaxf((float)hh[i], 0.f);
  __syncthreads();
  float s = fc1b[tid];
#pragma unroll 8
  for (int i = 0; i < Hh; ++i) s += fc1w[tid * Hh + i] * v[i];
  s = fmaxf(s, 0.f) * fc2w[tid];
#pragma unroll
  for (int off = 32; off; off >>= 1) s += __shfl_down(s, off);
  __shared__ float red[2];
  if ((tid & 63) == 0) red[tid >> 6] = s;
  __syncthreads();
  if (tid == 0) out[r] = red[0] + red[1] + fc2b[0];
}

extern "C" void kernel_launch(void* const* d_in, const int* in_sizes, int n_in,
                              void* d_out, int out_size, void* d_ws, size_t ws_size,
                              hipStream_t stream) {
  (void)in_sizes; (void)n_in; (void)out_size; (void)ws_size;
  const float* x    = (const float*)d_in[0];
  const float* wih0 = (const float*)d_in[1];
  const float* whh0 = (const float*)d_in[2];
  const float* bih0 = (const float*)d_in[3];
  const float* bhh0 = (const float*)d_in[4];
  const float* wih1 = (const float*)d_in[5];
  const float* whh1 = (const float*)d_in[6];
  const float* bih1 = (const float*)d_in[7];
  const float* bhh1 = (const float*)d_in[8];
  const float* fc1w = (const float*)d_in[9];
  const float* fc1b = (const float*)d_in[10];
  const float* fc2w = (const float*)d_in[11];
  const float* fc2b = (const float*)d_in[12];

  char* ws = (char*)d_ws;
  size_t off = 0;
  f16* xh = (f16*)(ws + off); off += (size_t)Bb * Tt * Dd * 2;
  f16* wfrag = (f16*)(ws + off); off += (size_t)16 * 8 * 32 * 512 * 2;
  float* bias0s = (float*)(ws + off); off += 4096;
  float* bias1s = (float*)(ws + off); off += 4096;
  char* zbase = ws + off;
  f16* h0 = (f16*)(ws + off); off += (size_t)4 * HB2 * 2;  // 4 slots
  f16* h1 = (f16*)(ws + off); off += (size_t)4 * HB2 * 2;  // 4 slots
  unsigned* flagcnt = (unsigned*)(ws + off); off += 256 * FSTRIDE * 4;  // 64B/cnt
  unsigned* probe = (unsigned*)(ws + off); off += 1024;
  unsigned* verdict = (unsigned*)(ws + off); off += 1024;
  size_t zbytes = (size_t)((ws + off) - zbase);

  hipMemsetAsync(zbase, 0, zbytes, stream);
  prep_x<<<Bb * Tt * Dd / 4 / 256, 256, 0, stream>>>(x, xh);
  prep_w<<<512, 256, 0, stream>>>(wih0, whh0, bih0, bhh0, wih1, whh1, bih1, bhh1,
                                  wfrag, bias0s, bias1s);
  lstm_persist<<<256, 512, 0, stream>>>(xh, wfrag, bias0s, bias1s, h0, h1,
                                        flagcnt, probe, verdict);
  // final h0 written at k=511 -> slot 3; final h1 at k=512 -> slot 0
  head_kernel<<<512, 128, 0, stream>>>(h0 + (size_t)3 * HB2, h1, fc1w, fc1b,
                                       fc2w, fc2b, (float*)d_out);
}